// Round 14
// baseline (276.444 us; speedup 1.0000x reference)
//
#include <hip/hip_runtime.h>
#include <hip/hip_bf16.h>

// Problem dims
#define Bd 16
#define Cd 3
#define Hd 64
#define Wd 64
#define Pd 256
#define PSd 9
#define Ed 256
#define NHd 8
#define DHd 32
#define HWd 4096
#define POSDd 64

typedef unsigned short u16;
typedef short short8 __attribute__((ext_vector_type(8)));
typedef float f32x4 __attribute__((ext_vector_type(4)));

__device__ __forceinline__ float bf2f(u16 u) {
    union { unsigned int i; float f; } c; c.i = ((unsigned int)u) << 16; return c.f;
}
__device__ __forceinline__ u16 f2bf(float f) {
    unsigned int x = __float_as_uint(f);
    unsigned int r = (x + 0x7fffu + ((x >> 16) & 1u)) >> 16;
    return (u16)r;
}

// ---------------------------------------------------------------------------
// prep_fused: all weight preprocessing in ONE kernel (grid-partitioned).
// ---------------------------------------------------------------------------
__global__ __launch_bounds__(256) void prep_fused(
    const float* __restrict__ conv_w, const float* __restrict__ in_w,
    const float* __restrict__ wq, const float* __restrict__ wk,
    const float* __restrict__ wv, const float* __restrict__ bq,
    const float* __restrict__ bk, const float* __restrict__ bv,
    const float* __restrict__ out_w, const float* __restrict__ fc_w,
    const float* __restrict__ out_b, const float* __restrict__ fc_b,
    u16* __restrict__ convw_h, u16* __restrict__ convw_l,
    u16* __restrict__ inw_h, u16* __restrict__ inw_l,
    u16* __restrict__ wqkv_h, u16* __restrict__ wqkv_l,
    float* __restrict__ bqkv, float* __restrict__ G, float* __restrict__ h0) {
    __shared__ u16 th[64][65];
    __shared__ u16 tl[64][65];
    int blk = blockIdx.x, t = threadIdx.x;

    if (blk < 256) {                       // conv weights
        float v = (t < 243) ? conv_w[blk * 243 + t] : 0.f;
        u16 h = f2bf(v);
        convw_h[blk * 256 + t] = h;
        convw_l[blk * 256 + t] = f2bf(v - bf2f(h));
    } else if (blk < 560) {                // transposes
        const float* W;
        u16 *Th, *Tl;
        int K, local;
        if (blk < 272)      { W = wq;   Th = wqkv_h;              Tl = wqkv_l;              K = 256;  local = blk - 256; }
        else if (blk < 288) { W = wk;   Th = wqkv_h + 256 * 256;  Tl = wqkv_l + 256 * 256;  K = 256;  local = blk - 272; }
        else if (blk < 304) { W = wv;   Th = wqkv_h + 512 * 256;  Tl = wqkv_l + 512 * 256;  K = 256;  local = blk - 288; }
        else                { W = in_w; Th = inw_h;               Tl = inw_l;               K = 4096; local = blk - 304; }
        int kt = (K == 256) ? (local & 3) : (local & 63);
        int nt = (K == 256) ? (local >> 2) : (local >> 6);
        int k0 = kt * 64, n0 = nt * 64;
        int col = t & 63, r4 = t >> 6;
        #pragma unroll
        for (int i = 0; i < 16; i++) {
            int kr = 4 * i + r4;
            float v = W[(size_t)(k0 + kr) * 256 + n0 + col];
            u16 h = f2bf(v);
            th[col][kr] = h;
            tl[col][kr] = f2bf(v - bf2f(h));
        }
        __syncthreads();
        #pragma unroll
        for (int i = 0; i < 16; i++) {
            int nr = 4 * i + r4;
            Th[(size_t)(n0 + nr) * K + k0 + col] = th[nr][col];
            Tl[(size_t)(n0 + nr) * K + k0 + col] = tl[nr][col];
        }
    } else if (blk == 560) {               // bias concat
        bqkv[t] = bq[t]; bqkv[256 + t] = bk[t]; bqkv[512 + t] = bv[t];
    } else if (blk < 625) {                // G, 4 e's per block (one per wave)
        int e = (blk - 561) * 4 + (t >> 6);
        int lane = t & 63;
        float a0 = 0.f, a1 = 0.f;
        for (int i = lane; i < HWd; i += 64) {
            float a = out_w[(size_t)e * HWd + i];
            a0 += a * fc_w[2 * i];
            a1 += a * fc_w[2 * i + 1];
        }
        #pragma unroll
        for (int off = 32; off; off >>= 1) { a0 += __shfl_xor(a0, off); a1 += __shfl_xor(a1, off); }
        if (lane == 0) { G[2 * e] = a0; G[2 * e + 1] = a1; }
    } else {                               // h0
        int wj = t >> 6, lane = t & 63;
        if (wj < 2) {
            float a = 0.f;
            for (int i = lane; i < HWd; i += 64) a += out_b[i] * fc_w[2 * i + wj];
            #pragma unroll
            for (int off = 32; off; off >>= 1) a += __shfl_xor(a, off);
            if (lane == 0) h0[wj] = a + fc_b[wj];
        }
    }
}

// ---------------------------------------------------------------------------
// K0b: M2[e][:] = sum_f wo[e,f]*G[f][:];  h0[j] += sum_e bo[e]*G[e][j]
// ---------------------------------------------------------------------------
__global__ __launch_bounds__(64) void precompute_M2(
    const float* __restrict__ wo, const float* __restrict__ bo,
    const float* __restrict__ G, float* __restrict__ M2, float* __restrict__ h0) {
    int blk = blockIdx.x, lane = threadIdx.x;
    if (blk < 256) {
        float m0 = 0.f, m1 = 0.f;
        for (int f = lane; f < Ed; f += 64) {
            float wv = wo[blk * Ed + f];
            m0 += wv * G[2 * f];
            m1 += wv * G[2 * f + 1];
        }
        #pragma unroll
        for (int off = 32; off; off >>= 1) { m0 += __shfl_xor(m0, off); m1 += __shfl_xor(m1, off); }
        if (lane == 0) { M2[2 * blk] = m0; M2[2 * blk + 1] = m1; }
    } else {
        int j = blk - 256;
        float hh = 0.f;
        for (int f = lane; f < Ed; f += 64) hh += bo[f] * G[2 * f + j];
        #pragma unroll
        for (int off = 32; off; off >>= 1) hh += __shfl_xor(hh, off);
        if (lane == 0) h0[j] += hh;
    }
}

// ---------------------------------------------------------------------------
// K1 v5: implicit-GEMM conv via MFMA (bf16x3), all 256 output channels/block.
// Single-barrier double-buffered sB: body = A-frags / build(next) /
// write sB[next] / mfma sB[cur] / barrier.  WAR on the write target is closed
// by the previous iter's end barrier; RAW on the mfma source by this iter's
// predecessor barrier.  Barriers 8 -> 5.  (256,3): no spills (the cap-128
// build spilled acc to 297MB scratch).
// ---------------------------------------------------------------------------
__global__ __launch_bounds__(256, 3) void conv_gemm(
    const u16* __restrict__ Ah, const u16* __restrict__ Al,
    const float* __restrict__ x, const float* __restrict__ conv_b,
    u16* __restrict__ feat_hi, u16* __restrict__ feat_lo) {
    __shared__ u16 sBh[2][64 * 72], sBl[2][64 * 72];
    __shared__ float wls[3 * 9 * 72];
    int tid = threadIdx.x;
    int w = tid >> 6, L = tid & 63;
    int m16 = L & 15, qd = L >> 4;
    int y = blockIdx.x;
    int nb = y << 6;
    int b = blockIdx.y;

    for (int i = tid; i < 3 * 9 * 72; i += 256) wls[i] = 0.f;
    __syncthreads();
    for (int i = tid; i < 3 * 9 * 64; i += 256) {
        int c = i / 576, rem = i - c * 576, wr = rem >> 6, col = rem & 63;
        int iy = y - 4 + wr;
        if (iy >= 0 && iy < 64)
            wls[c * 648 + wr * 72 + 4 + col] = x[((b * 3 + c) << 12) + (iy << 6) + col];
    }

    f32x4 acc[4][4];
    #pragma unroll
    for (int mt = 0; mt < 4; mt++)
        #pragma unroll
        for (int ct = 0; ct < 4; ct++) acc[mt][ct] = (f32x4){0.f, 0.f, 0.f, 0.f};

    int n = tid >> 2, kb = (tid & 3) << 4;
    int arow = w * 16 + m16;

    u16 hbuf[16] __attribute__((aligned(8)));
    u16 lbuf[16] __attribute__((aligned(8)));
    auto build = [&](int kbase) {
        #pragma unroll
        for (int j = 0; j < 16; j++) {
            int k = kbase + kb + j;
            float v = 0.f;
            if (k < 243) {
                int c = (k >= 81) + (k >= 162);
                int rem = k - c * 81;
                int dy = (rem * 57) >> 9;
                int dx = rem - dy * 9;
                v = wls[c * 648 + dy * 72 + dx + n];
            }
            u16 h = f2bf(v);
            hbuf[j] = h;
            lbuf[j] = f2bf(v - bf2f(h));
        }
    };
    auto store_sB = [&](int buf) {
        #pragma unroll
        for (int t = 0; t < 4; t++) {
            *(ushort4*)&sBh[buf][n * 72 + kb + 4 * t] = *(ushort4*)&hbuf[4 * t];
            *(ushort4*)&sBl[buf][n * 72 + kb + 4 * t] = *(ushort4*)&lbuf[4 * t];
        }
    };

    __syncthreads();        // wls staged (also covers first build's reads)
    build(0);
    store_sB(0);
    __syncthreads();        // sB[0] ready

    #pragma unroll
    for (int it = 0; it < 4; it++) {
        int k0 = it * 64;
        short8 afh[4][2], afl[4][2];
        #pragma unroll
        for (int mt = 0; mt < 4; mt++)
            #pragma unroll
            for (int c = 0; c < 2; c++) {
                int ao = (mt * 64 + arow) * 256 + k0 + c * 32 + qd * 8;
                afh[mt][c] = *(const short8*)(Ah + ao);
                afl[mt][c] = *(const short8*)(Al + ao);
            }
        if (it < 3) {                       // build+write NEXT buffer
            build(k0 + 64);
            store_sB((it + 1) & 1);
        }
        int cur = it & 1;
        #pragma unroll
        for (int c = 0; c < 2; c++) {
            #pragma unroll
            for (int ct = 0; ct < 4; ct++) {
                int bb = (ct * 16 + m16) * 72 + c * 32 + qd * 8;
                short8 bH = *(const short8*)&sBh[cur][bb];
                short8 bL = *(const short8*)&sBl[cur][bb];
                #pragma unroll
                for (int mt = 0; mt < 4; mt++) {
                    acc[mt][ct] = __builtin_amdgcn_mfma_f32_16x16x32_bf16(afh[mt][c], bH, acc[mt][ct], 0, 0, 0);
                    acc[mt][ct] = __builtin_amdgcn_mfma_f32_16x16x32_bf16(afh[mt][c], bL, acc[mt][ct], 0, 0, 0);
                    acc[mt][ct] = __builtin_amdgcn_mfma_f32_16x16x32_bf16(afl[mt][c], bH, acc[mt][ct], 0, 0, 0);
                }
            }
        }
        if (it < 3) __syncthreads();        // end-of-iter: next buffer ready,
                                            // current buffer's readers done
    }

    #pragma unroll
    for (int mt = 0; mt < 4; mt++) {
        #pragma unroll
        for (int i = 0; i < 4; i++) {
            int gr = mt * 64 + w * 16 + qd * 4 + i;
            float bv = conv_b[gr];
            #pragma unroll
            for (int ct = 0; ct < 4; ct++) {
                int gc = nb + ct * 16 + m16;
                float val = fmaxf(acc[mt][ct][i] + bv, 0.f);
                size_t oi = ((size_t)(b * 256 + gr)) * HWd + gc;
                u16 h = f2bf(val);
                feat_hi[oi] = h;
                feat_lo[oi] = f2bf(val - bf2f(h));
            }
        }
    }
}

// ---------------------------------------------------------------------------
// K2: bf16x3 MFMA GEMM with register prefetch + optional K-split (blockIdx.z).
// mode 0: Co = val + bias.  mode 1: Ch/Cl bf16 hi/lo (+bias).
// mode 2: Co[z*pstride + oi] = val (no bias) — fp32 partial for K-split.
// ---------------------------------------------------------------------------
__global__ __launch_bounds__(256, 4) void gemm_mfma3(
    const u16* __restrict__ Ah, const u16* __restrict__ Al,
    const u16* __restrict__ Bh, const u16* __restrict__ Bl,
    const float* __restrict__ bias,
    float* __restrict__ Co, u16* __restrict__ Ch, u16* __restrict__ Cl,
    int N, int K, int klen, long long pstride, int mode) {
    __shared__ u16 sAh[64 * 72], sAl[64 * 72], sBh[64 * 72], sBl[64 * 72];
    int tid = threadIdx.x;
    int w = tid >> 6;
    int L = tid & 63;
    int m16 = L & 15, qd = L >> 4;
    int mb = blockIdx.y * 64, nb = blockIdx.x * 64;
    int kbeg = blockIdx.z * klen;

    f32x4 acc[4];
    #pragma unroll
    for (int i = 0; i < 4; i++) acc[i] = (f32x4){0.f, 0.f, 0.f, 0.f};

    int r = tid >> 2, s = tid & 3;
    const u16* pAh = Ah + (size_t)(mb + r) * K + kbeg + s * 16;
    const u16* pAl = Al + (size_t)(mb + r) * K + kbeg + s * 16;
    const u16* pBh = Bh + (size_t)(nb + r) * K + kbeg + s * 16;
    const u16* pBl = Bl + (size_t)(nb + r) * K + kbeg + s * 16;
    u16* dAh = &sAh[r * 72 + s * 16];
    u16* dAl = &sAl[r * 72 + s * 16];
    u16* dBh = &sBh[r * 72 + s * 16];
    u16* dBl = &sBl[r * 72 + s * 16];

    uint4 a0 = *(const uint4*)(pAh);
    uint4 a1 = *(const uint4*)(pAh + 8);
    uint4 a2 = *(const uint4*)(pAl);
    uint4 a3 = *(const uint4*)(pAl + 8);
    uint4 b0 = *(const uint4*)(pBh);
    uint4 b1 = *(const uint4*)(pBh + 8);
    uint4 b2 = *(const uint4*)(pBl);
    uint4 b3 = *(const uint4*)(pBl + 8);

    for (int k0 = 0; k0 < klen; k0 += 64) {
        __syncthreads();
        *(uint4*)(dAh) = a0; *(uint4*)(dAh + 8) = a1;
        *(uint4*)(dAl) = a2; *(uint4*)(dAl + 8) = a3;
        *(uint4*)(dBh) = b0; *(uint4*)(dBh + 8) = b1;
        *(uint4*)(dBl) = b2; *(uint4*)(dBl + 8) = b3;
        __syncthreads();
        int kn = k0 + 64;
        if (kn < klen) {
            a0 = *(const uint4*)(pAh + kn);
            a1 = *(const uint4*)(pAh + kn + 8);
            a2 = *(const uint4*)(pAl + kn);
            a3 = *(const uint4*)(pAl + kn + 8);
            b0 = *(const uint4*)(pBh + kn);
            b1 = *(const uint4*)(pBh + kn + 8);
            b2 = *(const uint4*)(pBl + kn);
            b3 = *(const uint4*)(pBl + kn + 8);
        }
        #pragma unroll
        for (int c = 0; c < 2; c++) {
            int ab = (w * 16 + m16) * 72 + c * 32 + qd * 8;
            short8 aH = *(const short8*)&sAh[ab];
            short8 aL = *(const short8*)&sAl[ab];
            #pragma unroll
            for (int ct = 0; ct < 4; ct++) {
                int bb = (ct * 16 + m16) * 72 + c * 32 + qd * 8;
                short8 bH = *(const short8*)&sBh[bb];
                short8 bL = *(const short8*)&sBl[bb];
                acc[ct] = __builtin_amdgcn_mfma_f32_16x16x32_bf16(aH, bH, acc[ct], 0, 0, 0);
                acc[ct] = __builtin_amdgcn_mfma_f32_16x16x32_bf16(aH, bL, acc[ct], 0, 0, 0);
                acc[ct] = __builtin_amdgcn_mfma_f32_16x16x32_bf16(aL, bH, acc[ct], 0, 0, 0);
            }
        }
    }

    #pragma unroll
    for (int ct = 0; ct < 4; ct++) {
        int gc = nb + ct * 16 + m16;
        float bv = (mode == 2) ? 0.f : bias[gc];
        #pragma unroll
        for (int i = 0; i < 4; i++) {
            int gr = mb + w * 16 + qd * 4 + i;
            float val = acc[ct][i] + bv;
            size_t oi = (size_t)gr * N + gc;
            if (mode == 0) {
                Co[oi] = val;
            } else if (mode == 2) {
                Co[(size_t)blockIdx.z * pstride + oi] = val;
            } else {
                u16 h = f2bf(val);
                Ch[oi] = h;
                Cl[oi] = f2bf(val - bf2f(h));
            }
        }
    }
}

// ---------------------------------------------------------------------------
// K3: reduce 4 K-split partials + bias, emit bf16 hi/lo.  N=256 fixed.
// ---------------------------------------------------------------------------
__global__ __launch_bounds__(256) void reduce_split(
    const float* __restrict__ part, const float* __restrict__ bias,
    u16* __restrict__ Ch, u16* __restrict__ Cl, int total) {
    int i = (blockIdx.x * 256 + threadIdx.x) * 4;
    if (i >= total) return;
    float4 s0 = *(const float4*)(part + i);
    float4 s1 = *(const float4*)(part + (size_t)total + i);
    float4 s2 = *(const float4*)(part + 2 * (size_t)total + i);
    float4 s3 = *(const float4*)(part + 3 * (size_t)total + i);
    float4 bv = *(const float4*)(bias + (i & 255));
    float v[4] = { s0.x + s1.x + s2.x + s3.x + bv.x,
                   s0.y + s1.y + s2.y + s3.y + bv.y,
                   s0.z + s1.z + s2.z + s3.z + bv.z,
                   s0.w + s1.w + s2.w + s3.w + bv.w };
    u16 hb[4] __attribute__((aligned(8)));
    u16 lb[4] __attribute__((aligned(8)));
    #pragma unroll
    for (int j = 0; j < 4; j++) {
        u16 h = f2bf(v[j]);
        hb[j] = h;
        lb[j] = f2bf(v[j] - bf2f(h));
    }
    *(ushort4*)(Ch + i) = *(ushort4*)hb;
    *(ushort4*)(Cl + i) = *(ushort4*)lb;
}

// ---------------------------------------------------------------------------
// K4a: transpose V: qkv_h/l cols 512..767 -> vT[b][h][d][k] bf16 hi/lo.
// uint4 = 8 u16 — each thread owns a 32-elem k-segment => FOUR copies.
// ---------------------------------------------------------------------------
__global__ __launch_bounds__(256) void transpose_v(
    const u16* __restrict__ qkvh, const u16* __restrict__ qkvl,
    u16* __restrict__ vTh, u16* __restrict__ vTl) {
    __shared__ u16 th[32][264];
    __shared__ u16 tl[32][264];
    int b = blockIdx.x, h = blockIdx.y;
    int t = threadIdx.x;
    {
        const u16* srch = qkvh + ((size_t)(b * 256 + t)) * 768 + 512 + h * 32;
        const u16* srcl = qkvl + ((size_t)(b * 256 + t)) * 768 + 512 + h * 32;
        #pragma unroll
        for (int j = 0; j < 4; j++) {
            short8 vh = *(const short8*)(srch + j * 8);
            short8 vl = *(const short8*)(srcl + j * 8);
            #pragma unroll
            for (int e = 0; e < 8; e++) {
                th[j * 8 + e][t] = (u16)vh[e];
                tl[j * 8 + e][t] = (u16)vl[e];
            }
        }
    }
    __syncthreads();
    {
        int d = t >> 3, seg = t & 7;
        size_t dst = ((size_t)((b * 8 + h) * 32 + d)) * 256 + seg * 32;
        #pragma unroll
        for (int j = 0; j < 4; j++) {
            *(uint4*)(vTh + dst + j * 8) = *(uint4*)&th[d][seg * 32 + j * 8];
            *(uint4*)(vTl + dst + j * 8) = *(uint4*)&tl[d][seg * 32 + j * 8];
        }
    }
}

// ---------------------------------------------------------------------------
// K4b: MFMA attention.  grid (b, h, qc=4), 256 thr = 4 waves x 16 q-rows.
// ---------------------------------------------------------------------------
__global__ __launch_bounds__(256) void attention_mfma(
    const u16* __restrict__ qkvh, const u16* __restrict__ qkvl,
    const u16* __restrict__ vTh, const u16* __restrict__ vTl,
    float* __restrict__ o) {
    __shared__ u16 ph[4][16][264];
    int b = blockIdx.x, h = blockIdx.y, qc = blockIdx.z;
    int tid = threadIdx.x;
    int w = tid >> 6, L = tid & 63;
    int m16 = L & 15, qd = L >> 4;
    const float rs = 0.17677669529663687f;  // 1/sqrt(32)

    size_t qoff = ((size_t)(b * 256 + qc * 64 + w * 16 + m16)) * 768 + h * 32 + qd * 8;
    short8 qH = *(const short8*)(qkvh + qoff);
    short8 qL = *(const short8*)(qkvl + qoff);

    f32x4 sacc[16];
    #pragma unroll
    for (int nt = 0; nt < 16; nt++) {
        size_t koff = ((size_t)(b * 256 + nt * 16 + m16)) * 768 + 256 + h * 32 + qd * 8;
        short8 bH = *(const short8*)(qkvh + koff);
        short8 bL = *(const short8*)(qkvl + koff);
        f32x4 a = (f32x4){0.f, 0.f, 0.f, 0.f};
        a = __builtin_amdgcn_mfma_f32_16x16x32_bf16(qH, bH, a, 0, 0, 0);
        a = __builtin_amdgcn_mfma_f32_16x16x32_bf16(qH, bL, a, 0, 0, 0);
        a = __builtin_amdgcn_mfma_f32_16x16x32_bf16(qL, bH, a, 0, 0, 0);
        sacc[nt] = a;
    }

    float l4[4] = {0.f, 0.f, 0.f, 0.f};
    #pragma unroll
    for (int nt = 0; nt < 16; nt++)
        #pragma unroll
        for (int i = 0; i < 4; i++) {
            float p = __expf(sacc[nt][i] * rs);
            sacc[nt][i] = p;
            l4[i] += p;
        }
    #pragma unroll
    for (int i = 0; i < 4; i++) {
        l4[i] += __shfl_xor(l4[i], 1);
        l4[i] += __shfl_xor(l4[i], 2);
        l4[i] += __shfl_xor(l4[i], 4);
        l4[i] += __shfl_xor(l4[i], 8);
    }

    #pragma unroll
    for (int nt = 0; nt < 16; nt++)
        #pragma unroll
        for (int i = 0; i < 4; i++)
            ph[w][qd * 4 + i][nt * 16 + m16] = f2bf(sacc[nt][i]);

    f32x4 oacc[2];
    oacc[0] = (f32x4){0.f, 0.f, 0.f, 0.f};
    oacc[1] = (f32x4){0.f, 0.f, 0.f, 0.f};
    size_t vbase = ((size_t)(b * 8 + h)) * 32 * 256;
    #pragma unroll
    for (int kt = 0; kt < 8; kt++) {
        short8 pa = *(const short8*)&ph[w][m16][kt * 32 + qd * 8];
        #pragma unroll
        for (int ct = 0; ct < 2; ct++) {
            size_t voff = vbase + (size_t)(ct * 16 + m16) * 256 + kt * 32 + qd * 8;
            short8 vH = *(const short8*)(vTh + voff);
            short8 vL = *(const short8*)(vTl + voff);
            oacc[ct] = __builtin_amdgcn_mfma_f32_16x16x32_bf16(pa, vH, oacc[ct], 0, 0, 0);
            oacc[ct] = __builtin_amdgcn_mfma_f32_16x16x32_bf16(pa, vL, oacc[ct], 0, 0, 0);
        }
    }

    #pragma unroll
    for (int i = 0; i < 4; i++) {
        float rinv = 1.f / l4[i];
        int orow = b * 256 + qc * 64 + w * 16 + qd * 4 + i;
        #pragma unroll
        for (int ct = 0; ct < 2; ct++)
            o[(size_t)orow * 256 + h * 32 + ct * 16 + m16] = oacc[ct][i] * rinv;
    }
}

// ---------------------------------------------------------------------------
// K5: fused head. One wave per (b,p): tp = tanh(o@M2 + h0); pos embed; patches.
// ---------------------------------------------------------------------------
#define PATCH_OUT 995328   // 16*256*243
__global__ __launch_bounds__(256) void head_kernel(
    const float* __restrict__ o, const float* __restrict__ M2,
    const float* __restrict__ h0, const float* __restrict__ pos_w,
    const float* __restrict__ pos_b, const float* __restrict__ x,
    float* __restrict__ out) {
    int w = threadIdx.x >> 6, lane = threadIdx.x & 63;
    int bp = blockIdx.x * 4 + w;
    int b = bp >> 8;

    const float* orow = o + (size_t)bp * Ed;
    float4 o4 = *(const float4*)(orow + lane * 4);
    int e0 = lane * 4;
    float s0 = o4.x * M2[2 * e0 + 0] + o4.y * M2[2 * e0 + 2] + o4.z * M2[2 * e0 + 4] + o4.w * M2[2 * e0 + 6];
    float s1 = o4.x * M2[2 * e0 + 1] + o4.y * M2[2 * e0 + 3] + o4.z * M2[2 * e0 + 5] + o4.w * M2[2 * e0 + 7];
    #pragma unroll
    for (int off = 32; off; off >>= 1) { s0 += __shfl_xor(s0, off); s1 += __shfl_xor(s1, off); }

    float tx = tanhf(s0 + h0[0]);
    float ty = tanhf(s1 + h0[1]);

    {
        float pv = tx * pos_w[lane] + ty * pos_w[64 + lane] + pos_b[lane];
        out[PATCH_OUT + bp * POSDd + lane] = pv;
    }

    const float* xb = x + b * 3 * HWd;
    #pragma unroll
    for (int s = 0; s < 4; s++) {
        int idx = s * 64 + lane;
        if (idx < 243) {
            int c = idx / 81;
            int rem = idx - c * 81;
            int iy = rem / 9;
            int jx = rem - iy * 9;
            float basex = (2.f * jx + 1.f) / 9.f - 1.f;
            float basey = (2.f * iy + 1.f) / 9.f - 1.f;
            float gx = 0.140625f * basex + tx;
            float gy = 0.140625f * basey + ty;
            float ix  = ((gx + 1.f) * 64.f - 1.f) * 0.5f;
            float iyf = ((gy + 1.f) * 64.f - 1.f) * 0.5f;
            float x0f = floorf(ix), y0f = floorf(iyf);
            float wx = ix - x0f, wy = iyf - y0f;
            int x0i = min(max((int)x0f, 0), 63);
            int x1i = min(max((int)x0f + 1, 0), 63);
            int y0i = min(max((int)y0f, 0), 63);
            int y1i = min(max((int)y0f + 1, 0), 63);
            const float* xc = xb + c * HWd;
            float v00 = xc[y0i * Wd + x0i];
            float v01 = xc[y0i * Wd + x1i];
            float v10 = xc[y1i * Wd + x0i];
            float v11 = xc[y1i * Wd + x1i];
            float val = v00 * (1.f - wx) * (1.f - wy) + v01 * wx * (1.f - wy)
                      + v10 * (1.f - wx) * wy + v11 * wx * wy;
            out[bp * 243 + idx] = val;
        }
    }
}

// ---------------------------------------------------------------------------
extern "C" void kernel_launch(void* const* d_in, const int* in_sizes, int n_in,
                              void* d_out, int out_size, void* d_ws, size_t ws_size,
                              hipStream_t stream) {
    (void)in_sizes; (void)n_in; (void)out_size;
    const float* x      = (const float*)d_in[0];
    const float* conv_w = (const float*)d_in[1];
    const float* conv_b = (const float*)d_in[2];
    const float* in_w   = (const float*)d_in[3];
    const float* in_b   = (const float*)d_in[4];
    const float* wq     = (const float*)d_in[5];
    const float* bq     = (const float*)d_in[6];
    const float* wk     = (const float*)d_in[7];
    const float* bk     = (const float*)d_in[8];
    const float* wv     = (const float*)d_in[9];
    const float* bv     = (const float*)d_in[10];
    const float* wo     = (const float*)d_in[11];
    const float* bo     = (const float*)d_in[12];
    const float* out_w  = (const float*)d_in[13];
    const float* out_b  = (const float*)d_in[14];
    const float* fc_w   = (const float*)d_in[15];
    const float* fc_b   = (const float*)d_in[16];
    const float* pos_w  = (const float*)d_in[17];
    const float* pos_b  = (const float*)d_in[18];

    // ws sizing
    int CB = 16;
    for (;;) {
        size_t u16e = (size_t)(2 * CB + 4) * 1048576 + 2 * 196608 + 2 * 65536
                    + 2 * 3145728 + 2 * 1048576;
        size_t f32e = 768 + 1048576 + 4ull * CB * 65536 + 2048;
        if (u16e * 2 + f32e * 4 <= ws_size || CB == 1) break;
        CB >>= 1;
    }
    int nchunks = 16 / CB;

    char* base = (char*)d_ws;
    u16* feat_hi = (u16*)base;
    u16* feat_lo = feat_hi + (size_t)CB * 1048576;
    u16* tok_hi  = feat_lo + (size_t)CB * 1048576;
    u16* tok_lo  = tok_hi + 1048576;
    u16* inw_h   = tok_lo + 1048576;
    u16* inw_l   = inw_h + 1048576;
    u16* wqkv_h  = inw_l + 1048576;
    u16* wqkv_l  = wqkv_h + 196608;
    u16* convw_h = wqkv_l + 196608;
    u16* convw_l = convw_h + 65536;
    u16* qkvh    = convw_l + 65536;       // 3145728
    u16* qkvl    = qkvh + 3145728;
    u16* vTh     = qkvl + 3145728;        // 1048576
    u16* vTl     = vTh + 1048576;
    float* bqkv  = (float*)(vTl + 1048576);
    float* o     = bqkv + 768;
    float* part  = o + 1048576;           // 4*CB*65536 floats
    float* G     = part + 4ull * CB * 65536;
    float* M2    = G + 512;
    float* h0    = M2 + 512;
    float* out   = (float*)d_out;

    hipLaunchKernelGGL(prep_fused, dim3(626), dim3(256), 0, stream,
                       conv_w, in_w, wq, wk, wv, bq, bk, bv,
                       out_w, fc_w, out_b, fc_b,
                       convw_h, convw_l, inw_h, inw_l,
                       wqkv_h, wqkv_l, bqkv, G, h0);
    hipLaunchKernelGGL(precompute_M2, dim3(258), dim3(64), 0, stream,
                       wo, bo, G, M2, h0);

    for (int c = 0; c < nchunks; ++c) {
        hipLaunchKernelGGL(conv_gemm, dim3(64, CB), dim3(256), 0, stream,
                           convw_h, convw_l,
                           x + (size_t)c * CB * 3 * HWd, conv_b,
                           feat_hi, feat_lo);
        hipLaunchKernelGGL(gemm_mfma3, dim3(4, CB * 4, 4), dim3(256), 0, stream,
                           feat_hi, feat_lo, inw_h, inw_l, in_b,
                           part, (u16*)nullptr, (u16*)nullptr,
                           256, 4096, 1024, (long long)CB * 65536, 2);
        hipLaunchKernelGGL(reduce_split, dim3(CB * 65536 / 1024), dim3(256), 0, stream,
                           part, in_b,
                           tok_hi + (size_t)c * CB * 65536,
                           tok_lo + (size_t)c * CB * 65536,
                           CB * 65536);
    }
    // fused q|k|v GEMM -> bf16 hi/lo qkv
    hipLaunchKernelGGL(gemm_mfma3, dim3(12, 64, 1), dim3(256), 0, stream,
                       tok_hi, tok_lo, wqkv_h, wqkv_l, bqkv,
                       (float*)nullptr, qkvh, qkvl, 768, 256, 256, 0LL, 1);
    hipLaunchKernelGGL(transpose_v, dim3(16, 8), dim3(256), 0, stream,
                       qkvh, qkvl, vTh, vTl);
    hipLaunchKernelGGL(attention_mfma, dim3(16, 8, 4), dim3(256), 0, stream,
                       qkvh, qkvl, vTh, vTl, o);
    hipLaunchKernelGGL(head_kernel, dim3(1024), dim3(256), 0, stream,
                       o, M2, h0, pos_w, pos_b, x, out);
}

// Round 15
// 258.352 us; speedup vs baseline: 1.0700x; 1.0700x over previous
//
#include <hip/hip_runtime.h>
#include <hip/hip_bf16.h>

// Problem dims
#define Bd 16
#define Cd 3
#define Hd 64
#define Wd 64
#define Pd 256
#define PSd 9
#define Ed 256
#define NHd 8
#define DHd 32
#define HWd 4096
#define POSDd 64

typedef unsigned short u16;
typedef short short8 __attribute__((ext_vector_type(8)));
typedef float f32x4 __attribute__((ext_vector_type(4)));

__device__ __forceinline__ float bf2f(u16 u) {
    union { unsigned int i; float f; } c; c.i = ((unsigned int)u) << 16; return c.f;
}
__device__ __forceinline__ u16 f2bf(float f) {
    unsigned int x = __float_as_uint(f);
    unsigned int r = (x + 0x7fffu + ((x >> 16) & 1u)) >> 16;
    return (u16)r;
}

// ---------------------------------------------------------------------------
// prep_fused: all weight preprocessing in ONE kernel (grid-partitioned).
// ---------------------------------------------------------------------------
__global__ __launch_bounds__(256) void prep_fused(
    const float* __restrict__ conv_w, const float* __restrict__ in_w,
    const float* __restrict__ wq, const float* __restrict__ wk,
    const float* __restrict__ wv, const float* __restrict__ bq,
    const float* __restrict__ bk, const float* __restrict__ bv,
    const float* __restrict__ out_w, const float* __restrict__ fc_w,
    const float* __restrict__ out_b, const float* __restrict__ fc_b,
    u16* __restrict__ convw_h, u16* __restrict__ convw_l,
    u16* __restrict__ inw_h, u16* __restrict__ inw_l,
    u16* __restrict__ wqkv_h, u16* __restrict__ wqkv_l,
    float* __restrict__ bqkv, float* __restrict__ G, float* __restrict__ h0) {
    __shared__ u16 th[64][65];
    __shared__ u16 tl[64][65];
    int blk = blockIdx.x, t = threadIdx.x;

    if (blk < 256) {                       // conv weights
        float v = (t < 243) ? conv_w[blk * 243 + t] : 0.f;
        u16 h = f2bf(v);
        convw_h[blk * 256 + t] = h;
        convw_l[blk * 256 + t] = f2bf(v - bf2f(h));
    } else if (blk < 560) {                // transposes
        const float* W;
        u16 *Th, *Tl;
        int K, local;
        if (blk < 272)      { W = wq;   Th = wqkv_h;              Tl = wqkv_l;              K = 256;  local = blk - 256; }
        else if (blk < 288) { W = wk;   Th = wqkv_h + 256 * 256;  Tl = wqkv_l + 256 * 256;  K = 256;  local = blk - 272; }
        else if (blk < 304) { W = wv;   Th = wqkv_h + 512 * 256;  Tl = wqkv_l + 512 * 256;  K = 256;  local = blk - 288; }
        else                { W = in_w; Th = inw_h;               Tl = inw_l;               K = 4096; local = blk - 304; }
        int kt = (K == 256) ? (local & 3) : (local & 63);
        int nt = (K == 256) ? (local >> 2) : (local >> 6);
        int k0 = kt * 64, n0 = nt * 64;
        int col = t & 63, r4 = t >> 6;
        #pragma unroll
        for (int i = 0; i < 16; i++) {
            int kr = 4 * i + r4;
            float v = W[(size_t)(k0 + kr) * 256 + n0 + col];
            u16 h = f2bf(v);
            th[col][kr] = h;
            tl[col][kr] = f2bf(v - bf2f(h));
        }
        __syncthreads();
        #pragma unroll
        for (int i = 0; i < 16; i++) {
            int nr = 4 * i + r4;
            Th[(size_t)(n0 + nr) * K + k0 + col] = th[nr][col];
            Tl[(size_t)(n0 + nr) * K + k0 + col] = tl[nr][col];
        }
    } else if (blk == 560) {               // bias concat
        bqkv[t] = bq[t]; bqkv[256 + t] = bk[t]; bqkv[512 + t] = bv[t];
    } else if (blk < 625) {                // G, 4 e's per block (one per wave)
        int e = (blk - 561) * 4 + (t >> 6);
        int lane = t & 63;
        float a0 = 0.f, a1 = 0.f;
        for (int i = lane; i < HWd; i += 64) {
            float a = out_w[(size_t)e * HWd + i];
            a0 += a * fc_w[2 * i];
            a1 += a * fc_w[2 * i + 1];
        }
        #pragma unroll
        for (int off = 32; off; off >>= 1) { a0 += __shfl_xor(a0, off); a1 += __shfl_xor(a1, off); }
        if (lane == 0) { G[2 * e] = a0; G[2 * e + 1] = a1; }
    } else {                               // h0
        int wj = t >> 6, lane = t & 63;
        if (wj < 2) {
            float a = 0.f;
            for (int i = lane; i < HWd; i += 64) a += out_b[i] * fc_w[2 * i + wj];
            #pragma unroll
            for (int off = 32; off; off >>= 1) a += __shfl_xor(a, off);
            if (lane == 0) h0[wj] = a + fc_b[wj];
        }
    }
}

// ---------------------------------------------------------------------------
// K0b: M2[e][:] = sum_f wo[e,f]*G[f][:];  h0[j] += sum_e bo[e]*G[e][j]
// ---------------------------------------------------------------------------
__global__ __launch_bounds__(64) void precompute_M2(
    const float* __restrict__ wo, const float* __restrict__ bo,
    const float* __restrict__ G, float* __restrict__ M2, float* __restrict__ h0) {
    int blk = blockIdx.x, lane = threadIdx.x;
    if (blk < 256) {
        float m0 = 0.f, m1 = 0.f;
        for (int f = lane; f < Ed; f += 64) {
            float wv = wo[blk * Ed + f];
            m0 += wv * G[2 * f];
            m1 += wv * G[2 * f + 1];
        }
        #pragma unroll
        for (int off = 32; off; off >>= 1) { m0 += __shfl_xor(m0, off); m1 += __shfl_xor(m1, off); }
        if (lane == 0) { M2[2 * blk] = m0; M2[2 * blk + 1] = m1; }
    } else {
        int j = blk - 256;
        float hh = 0.f;
        for (int f = lane; f < Ed; f += 64) hh += bo[f] * G[2 * f + j];
        #pragma unroll
        for (int off = 32; off; off >>= 1) hh += __shfl_xor(hh, off);
        if (lane == 0) h0[j] += hh;
    }
}

// ---------------------------------------------------------------------------
// K1 (round-13 proven body): implicit-GEMM conv via MFMA (bf16x3), all 256
// output channels per block.  (256,3): no spills.  Two barriers per K-iter;
// next B-strip built between barriers (registers NOT held across the MFMA
// block — the round-14 single-barrier dbuf extended hbuf/lbuf live ranges
// across 96 MFMAs and spilled: FETCH +9MB / WRITE +17MB, 57->70us. Reverted.)
// ---------------------------------------------------------------------------
__global__ __launch_bounds__(256, 3) void conv_gemm(
    const u16* __restrict__ Ah, const u16* __restrict__ Al,
    const float* __restrict__ x, const float* __restrict__ conv_b,
    u16* __restrict__ feat_hi, u16* __restrict__ feat_lo) {
    __shared__ u16 sBh[64 * 72], sBl[64 * 72];
    __shared__ float wls[3 * 9 * 72];
    int tid = threadIdx.x;
    int w = tid >> 6, L = tid & 63;
    int m16 = L & 15, qd = L >> 4;
    int y = blockIdx.x;
    int nb = y << 6;
    int b = blockIdx.y;

    for (int i = tid; i < 3 * 9 * 72; i += 256) wls[i] = 0.f;
    __syncthreads();
    for (int i = tid; i < 3 * 9 * 64; i += 256) {
        int c = i / 576, rem = i - c * 576, wr = rem >> 6, col = rem & 63;
        int iy = y - 4 + wr;
        if (iy >= 0 && iy < 64)
            wls[c * 648 + wr * 72 + 4 + col] = x[((b * 3 + c) << 12) + (iy << 6) + col];
    }
    __syncthreads();

    f32x4 acc[4][4];
    #pragma unroll
    for (int mt = 0; mt < 4; mt++)
        #pragma unroll
        for (int ct = 0; ct < 4; ct++) acc[mt][ct] = (f32x4){0.f, 0.f, 0.f, 0.f};

    int n = tid >> 2, kb = (tid & 3) << 4;
    int arow = w * 16 + m16;

    u16 hbuf[16] __attribute__((aligned(8)));
    u16 lbuf[16] __attribute__((aligned(8)));
    auto build = [&](int kbase) {
        #pragma unroll
        for (int j = 0; j < 16; j++) {
            int k = kbase + kb + j;
            float v = 0.f;
            if (k < 243) {
                int c = (k >= 81) + (k >= 162);
                int rem = k - c * 81;
                int dy = (rem * 57) >> 9;
                int dx = rem - dy * 9;
                v = wls[c * 648 + dy * 72 + dx + n];
            }
            u16 h = f2bf(v);
            hbuf[j] = h;
            lbuf[j] = f2bf(v - bf2f(h));
        }
    };
    build(0);

    for (int k0 = 0; k0 < 256; k0 += 64) {
        short8 afh[4][2], afl[4][2];
        #pragma unroll
        for (int mt = 0; mt < 4; mt++)
            #pragma unroll
            for (int c = 0; c < 2; c++) {
                int ao = (mt * 64 + arow) * 256 + k0 + c * 32 + qd * 8;
                afh[mt][c] = *(const short8*)(Ah + ao);
                afl[mt][c] = *(const short8*)(Al + ao);
            }
        __syncthreads();                    // prior iter's sB reads done
        #pragma unroll
        for (int t = 0; t < 4; t++) {
            *(ushort4*)&sBh[n * 72 + kb + 4 * t] = *(ushort4*)&hbuf[4 * t];
            *(ushort4*)&sBl[n * 72 + kb + 4 * t] = *(ushort4*)&lbuf[4 * t];
        }
        __syncthreads();                    // sB ready
        if (k0 < 192) build(k0 + 64);       // overlaps MFMA below (indep regs)
        #pragma unroll
        for (int c = 0; c < 2; c++) {
            #pragma unroll
            for (int ct = 0; ct < 4; ct++) {
                int bb = (ct * 16 + m16) * 72 + c * 32 + qd * 8;
                short8 bH = *(const short8*)&sBh[bb];
                short8 bL = *(const short8*)&sBl[bb];
                #pragma unroll
                for (int mt = 0; mt < 4; mt++) {
                    acc[mt][ct] = __builtin_amdgcn_mfma_f32_16x16x32_bf16(afh[mt][c], bH, acc[mt][ct], 0, 0, 0);
                    acc[mt][ct] = __builtin_amdgcn_mfma_f32_16x16x32_bf16(afh[mt][c], bL, acc[mt][ct], 0, 0, 0);
                    acc[mt][ct] = __builtin_amdgcn_mfma_f32_16x16x32_bf16(afl[mt][c], bH, acc[mt][ct], 0, 0, 0);
                }
            }
        }
    }

    #pragma unroll
    for (int mt = 0; mt < 4; mt++) {
        #pragma unroll
        for (int i = 0; i < 4; i++) {
            int gr = mt * 64 + w * 16 + qd * 4 + i;
            float bv = conv_b[gr];
            #pragma unroll
            for (int ct = 0; ct < 4; ct++) {
                int gc = nb + ct * 16 + m16;
                float val = fmaxf(acc[mt][ct][i] + bv, 0.f);
                size_t oi = ((size_t)(b * 256 + gr)) * HWd + gc;
                u16 h = f2bf(val);
                feat_hi[oi] = h;
                feat_lo[oi] = f2bf(val - bf2f(h));
            }
        }
    }
}

// ---------------------------------------------------------------------------
// K2: bf16x3 MFMA GEMM with register prefetch + optional K-split (blockIdx.z).
// mode 0: Co = val + bias.  mode 1: Ch/Cl bf16 hi/lo (+bias).
// mode 2: Co[z*pstride + oi] = val (no bias) — fp32 partial for K-split.
// ---------------------------------------------------------------------------
__global__ __launch_bounds__(256, 4) void gemm_mfma3(
    const u16* __restrict__ Ah, const u16* __restrict__ Al,
    const u16* __restrict__ Bh, const u16* __restrict__ Bl,
    const float* __restrict__ bias,
    float* __restrict__ Co, u16* __restrict__ Ch, u16* __restrict__ Cl,
    int N, int K, int klen, long long pstride, int mode) {
    __shared__ u16 sAh[64 * 72], sAl[64 * 72], sBh[64 * 72], sBl[64 * 72];
    int tid = threadIdx.x;
    int w = tid >> 6;
    int L = tid & 63;
    int m16 = L & 15, qd = L >> 4;
    int mb = blockIdx.y * 64, nb = blockIdx.x * 64;
    int kbeg = blockIdx.z * klen;

    f32x4 acc[4];
    #pragma unroll
    for (int i = 0; i < 4; i++) acc[i] = (f32x4){0.f, 0.f, 0.f, 0.f};

    int r = tid >> 2, s = tid & 3;
    const u16* pAh = Ah + (size_t)(mb + r) * K + kbeg + s * 16;
    const u16* pAl = Al + (size_t)(mb + r) * K + kbeg + s * 16;
    const u16* pBh = Bh + (size_t)(nb + r) * K + kbeg + s * 16;
    const u16* pBl = Bl + (size_t)(nb + r) * K + kbeg + s * 16;
    u16* dAh = &sAh[r * 72 + s * 16];
    u16* dAl = &sAl[r * 72 + s * 16];
    u16* dBh = &sBh[r * 72 + s * 16];
    u16* dBl = &sBl[r * 72 + s * 16];

    uint4 a0 = *(const uint4*)(pAh);
    uint4 a1 = *(const uint4*)(pAh + 8);
    uint4 a2 = *(const uint4*)(pAl);
    uint4 a3 = *(const uint4*)(pAl + 8);
    uint4 b0 = *(const uint4*)(pBh);
    uint4 b1 = *(const uint4*)(pBh + 8);
    uint4 b2 = *(const uint4*)(pBl);
    uint4 b3 = *(const uint4*)(pBl + 8);

    for (int k0 = 0; k0 < klen; k0 += 64) {
        __syncthreads();
        *(uint4*)(dAh) = a0; *(uint4*)(dAh + 8) = a1;
        *(uint4*)(dAl) = a2; *(uint4*)(dAl + 8) = a3;
        *(uint4*)(dBh) = b0; *(uint4*)(dBh + 8) = b1;
        *(uint4*)(dBl) = b2; *(uint4*)(dBl + 8) = b3;
        __syncthreads();
        int kn = k0 + 64;
        if (kn < klen) {
            a0 = *(const uint4*)(pAh + kn);
            a1 = *(const uint4*)(pAh + kn + 8);
            a2 = *(const uint4*)(pAl + kn);
            a3 = *(const uint4*)(pAl + kn + 8);
            b0 = *(const uint4*)(pBh + kn);
            b1 = *(const uint4*)(pBh + kn + 8);
            b2 = *(const uint4*)(pBl + kn);
            b3 = *(const uint4*)(pBl + kn + 8);
        }
        #pragma unroll
        for (int c = 0; c < 2; c++) {
            int ab = (w * 16 + m16) * 72 + c * 32 + qd * 8;
            short8 aH = *(const short8*)&sAh[ab];
            short8 aL = *(const short8*)&sAl[ab];
            #pragma unroll
            for (int ct = 0; ct < 4; ct++) {
                int bb = (ct * 16 + m16) * 72 + c * 32 + qd * 8;
                short8 bH = *(const short8*)&sBh[bb];
                short8 bL = *(const short8*)&sBl[bb];
                acc[ct] = __builtin_amdgcn_mfma_f32_16x16x32_bf16(aH, bH, acc[ct], 0, 0, 0);
                acc[ct] = __builtin_amdgcn_mfma_f32_16x16x32_bf16(aH, bL, acc[ct], 0, 0, 0);
                acc[ct] = __builtin_amdgcn_mfma_f32_16x16x32_bf16(aL, bH, acc[ct], 0, 0, 0);
            }
        }
    }

    #pragma unroll
    for (int ct = 0; ct < 4; ct++) {
        int gc = nb + ct * 16 + m16;
        float bv = (mode == 2) ? 0.f : bias[gc];
        #pragma unroll
        for (int i = 0; i < 4; i++) {
            int gr = mb + w * 16 + qd * 4 + i;
            float val = acc[ct][i] + bv;
            size_t oi = (size_t)gr * N + gc;
            if (mode == 0) {
                Co[oi] = val;
            } else if (mode == 2) {
                Co[(size_t)blockIdx.z * pstride + oi] = val;
            } else {
                u16 h = f2bf(val);
                Ch[oi] = h;
                Cl[oi] = f2bf(val - bf2f(h));
            }
        }
    }
}

// ---------------------------------------------------------------------------
// K3: reduce 4 K-split partials + bias, emit bf16 hi/lo.  N=256 fixed.
// ---------------------------------------------------------------------------
__global__ __launch_bounds__(256) void reduce_split(
    const float* __restrict__ part, const float* __restrict__ bias,
    u16* __restrict__ Ch, u16* __restrict__ Cl, int total) {
    int i = (blockIdx.x * 256 + threadIdx.x) * 4;
    if (i >= total) return;
    float4 s0 = *(const float4*)(part + i);
    float4 s1 = *(const float4*)(part + (size_t)total + i);
    float4 s2 = *(const float4*)(part + 2 * (size_t)total + i);
    float4 s3 = *(const float4*)(part + 3 * (size_t)total + i);
    float4 bv = *(const float4*)(bias + (i & 255));
    float v[4] = { s0.x + s1.x + s2.x + s3.x + bv.x,
                   s0.y + s1.y + s2.y + s3.y + bv.y,
                   s0.z + s1.z + s2.z + s3.z + bv.z,
                   s0.w + s1.w + s2.w + s3.w + bv.w };
    u16 hb[4] __attribute__((aligned(8)));
    u16 lb[4] __attribute__((aligned(8)));
    #pragma unroll
    for (int j = 0; j < 4; j++) {
        u16 h = f2bf(v[j]);
        hb[j] = h;
        lb[j] = f2bf(v[j] - bf2f(h));
    }
    *(ushort4*)(Ch + i) = *(ushort4*)hb;
    *(ushort4*)(Cl + i) = *(ushort4*)lb;
}

// ---------------------------------------------------------------------------
// K4a: transpose V: qkv_h/l cols 512..767 -> vT[b][h][d][k] bf16 hi/lo.
// uint4 = 8 u16 — each thread owns a 32-elem k-segment => FOUR copies.
// ---------------------------------------------------------------------------
__global__ __launch_bounds__(256) void transpose_v(
    const u16* __restrict__ qkvh, const u16* __restrict__ qkvl,
    u16* __restrict__ vTh, u16* __restrict__ vTl) {
    __shared__ u16 th[32][264];
    __shared__ u16 tl[32][264];
    int b = blockIdx.x, h = blockIdx.y;
    int t = threadIdx.x;
    {
        const u16* srch = qkvh + ((size_t)(b * 256 + t)) * 768 + 512 + h * 32;
        const u16* srcl = qkvl + ((size_t)(b * 256 + t)) * 768 + 512 + h * 32;
        #pragma unroll
        for (int j = 0; j < 4; j++) {
            short8 vh = *(const short8*)(srch + j * 8);
            short8 vl = *(const short8*)(srcl + j * 8);
            #pragma unroll
            for (int e = 0; e < 8; e++) {
                th[j * 8 + e][t] = (u16)vh[e];
                tl[j * 8 + e][t] = (u16)vl[e];
            }
        }
    }
    __syncthreads();
    {
        int d = t >> 3, seg = t & 7;
        size_t dst = ((size_t)((b * 8 + h) * 32 + d)) * 256 + seg * 32;
        #pragma unroll
        for (int j = 0; j < 4; j++) {
            *(uint4*)(vTh + dst + j * 8) = *(uint4*)&th[d][seg * 32 + j * 8];
            *(uint4*)(vTl + dst + j * 8) = *(uint4*)&tl[d][seg * 32 + j * 8];
        }
    }
}

// ---------------------------------------------------------------------------
// K4b: MFMA attention.  grid (b, h, qc=4), 256 thr = 4 waves x 16 q-rows.
// ---------------------------------------------------------------------------
__global__ __launch_bounds__(256) void attention_mfma(
    const u16* __restrict__ qkvh, const u16* __restrict__ qkvl,
    const u16* __restrict__ vTh, const u16* __restrict__ vTl,
    float* __restrict__ o) {
    __shared__ u16 ph[4][16][264];
    int b = blockIdx.x, h = blockIdx.y, qc = blockIdx.z;
    int tid = threadIdx.x;
    int w = tid >> 6, L = tid & 63;
    int m16 = L & 15, qd = L >> 4;
    const float rs = 0.17677669529663687f;  // 1/sqrt(32)

    size_t qoff = ((size_t)(b * 256 + qc * 64 + w * 16 + m16)) * 768 + h * 32 + qd * 8;
    short8 qH = *(const short8*)(qkvh + qoff);
    short8 qL = *(const short8*)(qkvl + qoff);

    f32x4 sacc[16];
    #pragma unroll
    for (int nt = 0; nt < 16; nt++) {
        size_t koff = ((size_t)(b * 256 + nt * 16 + m16)) * 768 + 256 + h * 32 + qd * 8;
        short8 bH = *(const short8*)(qkvh + koff);
        short8 bL = *(const short8*)(qkvl + koff);
        f32x4 a = (f32x4){0.f, 0.f, 0.f, 0.f};
        a = __builtin_amdgcn_mfma_f32_16x16x32_bf16(qH, bH, a, 0, 0, 0);
        a = __builtin_amdgcn_mfma_f32_16x16x32_bf16(qH, bL, a, 0, 0, 0);
        a = __builtin_amdgcn_mfma_f32_16x16x32_bf16(qL, bH, a, 0, 0, 0);
        sacc[nt] = a;
    }

    float l4[4] = {0.f, 0.f, 0.f, 0.f};
    #pragma unroll
    for (int nt = 0; nt < 16; nt++)
        #pragma unroll
        for (int i = 0; i < 4; i++) {
            float p = __expf(sacc[nt][i] * rs);
            sacc[nt][i] = p;
            l4[i] += p;
        }
    #pragma unroll
    for (int i = 0; i < 4; i++) {
        l4[i] += __shfl_xor(l4[i], 1);
        l4[i] += __shfl_xor(l4[i], 2);
        l4[i] += __shfl_xor(l4[i], 4);
        l4[i] += __shfl_xor(l4[i], 8);
    }

    #pragma unroll
    for (int nt = 0; nt < 16; nt++)
        #pragma unroll
        for (int i = 0; i < 4; i++)
            ph[w][qd * 4 + i][nt * 16 + m16] = f2bf(sacc[nt][i]);

    f32x4 oacc[2];
    oacc[0] = (f32x4){0.f, 0.f, 0.f, 0.f};
    oacc[1] = (f32x4){0.f, 0.f, 0.f, 0.f};
    size_t vbase = ((size_t)(b * 8 + h)) * 32 * 256;
    #pragma unroll
    for (int kt = 0; kt < 8; kt++) {
        short8 pa = *(const short8*)&ph[w][m16][kt * 32 + qd * 8];
        #pragma unroll
        for (int ct = 0; ct < 2; ct++) {
            size_t voff = vbase + (size_t)(ct * 16 + m16) * 256 + kt * 32 + qd * 8;
            short8 vH = *(const short8*)(vTh + voff);
            short8 vL = *(const short8*)(vTl + voff);
            oacc[ct] = __builtin_amdgcn_mfma_f32_16x16x32_bf16(pa, vH, oacc[ct], 0, 0, 0);
            oacc[ct] = __builtin_amdgcn_mfma_f32_16x16x32_bf16(pa, vL, oacc[ct], 0, 0, 0);
        }
    }

    #pragma unroll
    for (int i = 0; i < 4; i++) {
        float rinv = 1.f / l4[i];
        int orow = b * 256 + qc * 64 + w * 16 + qd * 4 + i;
        #pragma unroll
        for (int ct = 0; ct < 2; ct++)
            o[(size_t)orow * 256 + h * 32 + ct * 16 + m16] = oacc[ct][i] * rinv;
    }
}

// ---------------------------------------------------------------------------
// K5: fused head. One wave per (b,p): tp = tanh(o@M2 + h0); pos embed; patches.
// ---------------------------------------------------------------------------
#define PATCH_OUT 995328   // 16*256*243
__global__ __launch_bounds__(256) void head_kernel(
    const float* __restrict__ o, const float* __restrict__ M2,
    const float* __restrict__ h0, const float* __restrict__ pos_w,
    const float* __restrict__ pos_b, const float* __restrict__ x,
    float* __restrict__ out) {
    int w = threadIdx.x >> 6, lane = threadIdx.x & 63;
    int bp = blockIdx.x * 4 + w;
    int b = bp >> 8;

    const float* orow = o + (size_t)bp * Ed;
    float4 o4 = *(const float4*)(orow + lane * 4);
    int e0 = lane * 4;
    float s0 = o4.x * M2[2 * e0 + 0] + o4.y * M2[2 * e0 + 2] + o4.z * M2[2 * e0 + 4] + o4.w * M2[2 * e0 + 6];
    float s1 = o4.x * M2[2 * e0 + 1] + o4.y * M2[2 * e0 + 3] + o4.z * M2[2 * e0 + 5] + o4.w * M2[2 * e0 + 7];
    #pragma unroll
    for (int off = 32; off; off >>= 1) { s0 += __shfl_xor(s0, off); s1 += __shfl_xor(s1, off); }

    float tx = tanhf(s0 + h0[0]);
    float ty = tanhf(s1 + h0[1]);

    {
        float pv = tx * pos_w[lane] + ty * pos_w[64 + lane] + pos_b[lane];
        out[PATCH_OUT + bp * POSDd + lane] = pv;
    }

    const float* xb = x + b * 3 * HWd;
    #pragma unroll
    for (int s = 0; s < 4; s++) {
        int idx = s * 64 + lane;
        if (idx < 243) {
            int c = idx / 81;
            int rem = idx - c * 81;
            int iy = rem / 9;
            int jx = rem - iy * 9;
            float basex = (2.f * jx + 1.f) / 9.f - 1.f;
            float basey = (2.f * iy + 1.f) / 9.f - 1.f;
            float gx = 0.140625f * basex + tx;
            float gy = 0.140625f * basey + ty;
            float ix  = ((gx + 1.f) * 64.f - 1.f) * 0.5f;
            float iyf = ((gy + 1.f) * 64.f - 1.f) * 0.5f;
            float x0f = floorf(ix), y0f = floorf(iyf);
            float wx = ix - x0f, wy = iyf - y0f;
            int x0i = min(max((int)x0f, 0), 63);
            int x1i = min(max((int)x0f + 1, 0), 63);
            int y0i = min(max((int)y0f, 0), 63);
            int y1i = min(max((int)y0f + 1, 0), 63);
            const float* xc = xb + c * HWd;
            float v00 = xc[y0i * Wd + x0i];
            float v01 = xc[y0i * Wd + x1i];
            float v10 = xc[y1i * Wd + x0i];
            float v11 = xc[y1i * Wd + x1i];
            float val = v00 * (1.f - wx) * (1.f - wy) + v01 * wx * (1.f - wy)
                      + v10 * (1.f - wx) * wy + v11 * wx * wy;
            out[bp * 243 + idx] = val;
        }
    }
}

// ---------------------------------------------------------------------------
extern "C" void kernel_launch(void* const* d_in, const int* in_sizes, int n_in,
                              void* d_out, int out_size, void* d_ws, size_t ws_size,
                              hipStream_t stream) {
    (void)in_sizes; (void)n_in; (void)out_size;
    const float* x      = (const float*)d_in[0];
    const float* conv_w = (const float*)d_in[1];
    const float* conv_b = (const float*)d_in[2];
    const float* in_w   = (const float*)d_in[3];
    const float* in_b   = (const float*)d_in[4];
    const float* wq     = (const float*)d_in[5];
    const float* bq     = (const float*)d_in[6];
    const float* wk     = (const float*)d_in[7];
    const float* bk     = (const float*)d_in[8];
    const float* wv     = (const float*)d_in[9];
    const float* bv     = (const float*)d_in[10];
    const float* wo     = (const float*)d_in[11];
    const float* bo     = (const float*)d_in[12];
    const float* out_w  = (const float*)d_in[13];
    const float* out_b  = (const float*)d_in[14];
    const float* fc_w   = (const float*)d_in[15];
    const float* fc_b   = (const float*)d_in[16];
    const float* pos_w  = (const float*)d_in[17];
    const float* pos_b  = (const float*)d_in[18];

    // ws sizing
    int CB = 16;
    for (;;) {
        size_t u16e = (size_t)(2 * CB + 4) * 1048576 + 2 * 196608 + 2 * 65536
                    + 2 * 3145728 + 2 * 1048576;
        size_t f32e = 768 + 1048576 + 4ull * CB * 65536 + 2048;
        if (u16e * 2 + f32e * 4 <= ws_size || CB == 1) break;
        CB >>= 1;
    }
    int nchunks = 16 / CB;

    char* base = (char*)d_ws;
    u16* feat_hi = (u16*)base;
    u16* feat_lo = feat_hi + (size_t)CB * 1048576;
    u16* tok_hi  = feat_lo + (size_t)CB * 1048576;
    u16* tok_lo  = tok_hi + 1048576;
    u16* inw_h   = tok_lo + 1048576;
    u16* inw_l   = inw_h + 1048576;
    u16* wqkv_h  = inw_l + 1048576;
    u16* wqkv_l  = wqkv_h + 196608;
    u16* convw_h = wqkv_l + 196608;
    u16* convw_l = convw_h + 65536;
    u16* qkvh    = convw_l + 65536;       // 3145728
    u16* qkvl    = qkvh + 3145728;
    u16* vTh     = qkvl + 3145728;        // 1048576
    u16* vTl     = vTh + 1048576;
    float* bqkv  = (float*)(vTl + 1048576);
    float* o     = bqkv + 768;
    float* part  = o + 1048576;           // 4*CB*65536 floats
    float* G     = part + 4ull * CB * 65536;
    float* M2    = G + 512;
    float* h0    = M2 + 512;
    float* out   = (float*)d_out;

    hipLaunchKernelGGL(prep_fused, dim3(626), dim3(256), 0, stream,
                       conv_w, in_w, wq, wk, wv, bq, bk, bv,
                       out_w, fc_w, out_b, fc_b,
                       convw_h, convw_l, inw_h, inw_l,
                       wqkv_h, wqkv_l, bqkv, G, h0);
    hipLaunchKernelGGL(precompute_M2, dim3(258), dim3(64), 0, stream,
                       wo, bo, G, M2, h0);

    for (int c = 0; c < nchunks; ++c) {
        hipLaunchKernelGGL(conv_gemm, dim3(64, CB), dim3(256), 0, stream,
                           convw_h, convw_l,
                           x + (size_t)c * CB * 3 * HWd, conv_b,
                           feat_hi, feat_lo);
        hipLaunchKernelGGL(gemm_mfma3, dim3(4, CB * 4, 4), dim3(256), 0, stream,
                           feat_hi, feat_lo, inw_h, inw_l, in_b,
                           part, (u16*)nullptr, (u16*)nullptr,
                           256, 4096, 1024, (long long)CB * 65536, 2);
        hipLaunchKernelGGL(reduce_split, dim3(CB * 65536 / 1024), dim3(256), 0, stream,
                           part, in_b,
                           tok_hi + (size_t)c * CB * 65536,
                           tok_lo + (size_t)c * CB * 65536,
                           CB * 65536);
    }
    // fused q|k|v GEMM -> bf16 hi/lo qkv
    hipLaunchKernelGGL(gemm_mfma3, dim3(12, 64, 1), dim3(256), 0, stream,
                       tok_hi, tok_lo, wqkv_h, wqkv_l, bqkv,
                       (float*)nullptr, qkvh, qkvl, 768, 256, 256, 0LL, 1);
    hipLaunchKernelGGL(transpose_v, dim3(16, 8), dim3(256), 0, stream,
                       qkvh, qkvl, vTh, vTl);
    hipLaunchKernelGGL(attention_mfma, dim3(16, 8, 4), dim3(256), 0, stream,
                       qkvh, qkvl, vTh, vTl, o);
    hipLaunchKernelGGL(head_kernel, dim3(1024), dim3(256), 0, stream,
                       o, M2, h0, pos_w, pos_b, x, out);
}

// Round 16
// 244.102 us; speedup vs baseline: 1.1325x; 1.0584x over previous
//
#include <hip/hip_runtime.h>
#include <hip/hip_bf16.h>

// Problem dims
#define Bd 16
#define Cd 3
#define Hd 64
#define Wd 64
#define Pd 256
#define PSd 9
#define Ed 256
#define NHd 8
#define DHd 32
#define HWd 4096
#define POSDd 64

typedef unsigned short u16;
typedef short short8 __attribute__((ext_vector_type(8)));
typedef float f32x4 __attribute__((ext_vector_type(4)));

__device__ __forceinline__ float bf2f(u16 u) {
    union { unsigned int i; float f; } c; c.i = ((unsigned int)u) << 16; return c.f;
}
__device__ __forceinline__ u16 f2bf(float f) {
    unsigned int x = __float_as_uint(f);
    unsigned int r = (x + 0x7fffu + ((x >> 16) & 1u)) >> 16;
    return (u16)r;
}

// ---------------------------------------------------------------------------
// prep_fused: all weight preprocessing in ONE kernel (grid-partitioned).
// ---------------------------------------------------------------------------
__global__ __launch_bounds__(256) void prep_fused(
    const float* __restrict__ conv_w, const float* __restrict__ in_w,
    const float* __restrict__ wq, const float* __restrict__ wk,
    const float* __restrict__ wv, const float* __restrict__ bq,
    const float* __restrict__ bk, const float* __restrict__ bv,
    const float* __restrict__ out_w, const float* __restrict__ fc_w,
    const float* __restrict__ out_b, const float* __restrict__ fc_b,
    u16* __restrict__ convw_h, u16* __restrict__ convw_l,
    u16* __restrict__ inw_h, u16* __restrict__ inw_l,
    u16* __restrict__ wqkv_h, u16* __restrict__ wqkv_l,
    float* __restrict__ bqkv, float* __restrict__ G, float* __restrict__ h0) {
    __shared__ u16 th[64][65];
    __shared__ u16 tl[64][65];
    int blk = blockIdx.x, t = threadIdx.x;

    if (blk < 256) {                       // conv weights
        float v = (t < 243) ? conv_w[blk * 243 + t] : 0.f;
        u16 h = f2bf(v);
        convw_h[blk * 256 + t] = h;
        convw_l[blk * 256 + t] = f2bf(v - bf2f(h));
    } else if (blk < 560) {                // transposes
        const float* W;
        u16 *Th, *Tl;
        int K, local;
        if (blk < 272)      { W = wq;   Th = wqkv_h;              Tl = wqkv_l;              K = 256;  local = blk - 256; }
        else if (blk < 288) { W = wk;   Th = wqkv_h + 256 * 256;  Tl = wqkv_l + 256 * 256;  K = 256;  local = blk - 272; }
        else if (blk < 304) { W = wv;   Th = wqkv_h + 512 * 256;  Tl = wqkv_l + 512 * 256;  K = 256;  local = blk - 288; }
        else                { W = in_w; Th = inw_h;               Tl = inw_l;               K = 4096; local = blk - 304; }
        int kt = (K == 256) ? (local & 3) : (local & 63);
        int nt = (K == 256) ? (local >> 2) : (local >> 6);
        int k0 = kt * 64, n0 = nt * 64;
        int col = t & 63, r4 = t >> 6;
        #pragma unroll
        for (int i = 0; i < 16; i++) {
            int kr = 4 * i + r4;
            float v = W[(size_t)(k0 + kr) * 256 + n0 + col];
            u16 h = f2bf(v);
            th[col][kr] = h;
            tl[col][kr] = f2bf(v - bf2f(h));
        }
        __syncthreads();
        #pragma unroll
        for (int i = 0; i < 16; i++) {
            int nr = 4 * i + r4;
            Th[(size_t)(n0 + nr) * K + k0 + col] = th[nr][col];
            Tl[(size_t)(n0 + nr) * K + k0 + col] = tl[nr][col];
        }
    } else if (blk == 560) {               // bias concat
        bqkv[t] = bq[t]; bqkv[256 + t] = bk[t]; bqkv[512 + t] = bv[t];
    } else if (blk < 625) {                // G, 4 e's per block (one per wave)
        int e = (blk - 561) * 4 + (t >> 6);
        int lane = t & 63;
        float a0 = 0.f, a1 = 0.f;
        for (int i = lane; i < HWd; i += 64) {
            float a = out_w[(size_t)e * HWd + i];
            a0 += a * fc_w[2 * i];
            a1 += a * fc_w[2 * i + 1];
        }
        #pragma unroll
        for (int off = 32; off; off >>= 1) { a0 += __shfl_xor(a0, off); a1 += __shfl_xor(a1, off); }
        if (lane == 0) { G[2 * e] = a0; G[2 * e + 1] = a1; }
    } else {                               // h0
        int wj = t >> 6, lane = t & 63;
        if (wj < 2) {
            float a = 0.f;
            for (int i = lane; i < HWd; i += 64) a += out_b[i] * fc_w[2 * i + wj];
            #pragma unroll
            for (int off = 32; off; off >>= 1) a += __shfl_xor(a, off);
            if (lane == 0) h0[wj] = a + fc_b[wj];
        }
    }
}

// ---------------------------------------------------------------------------
// K0b: M2[e][:] = sum_f wo[e,f]*G[f][:];  h0[j] += sum_e bo[e]*G[e][j]
// ---------------------------------------------------------------------------
__global__ __launch_bounds__(64) void precompute_M2(
    const float* __restrict__ wo, const float* __restrict__ bo,
    const float* __restrict__ G, float* __restrict__ M2, float* __restrict__ h0) {
    int blk = blockIdx.x, lane = threadIdx.x;
    if (blk < 256) {
        float m0 = 0.f, m1 = 0.f;
        for (int f = lane; f < Ed; f += 64) {
            float wv = wo[blk * Ed + f];
            m0 += wv * G[2 * f];
            m1 += wv * G[2 * f + 1];
        }
        #pragma unroll
        for (int off = 32; off; off >>= 1) { m0 += __shfl_xor(m0, off); m1 += __shfl_xor(m1, off); }
        if (lane == 0) { M2[2 * blk] = m0; M2[2 * blk + 1] = m1; }
    } else {
        int j = blk - 256;
        float hh = 0.f;
        for (int f = lane; f < Ed; f += 64) hh += bo[f] * G[2 * f + j];
        #pragma unroll
        for (int off = 32; off; off >>= 1) hh += __shfl_xor(hh, off);
        if (lane == 0) h0[j] += hh;
    }
}

// ---------------------------------------------------------------------------
// K1 (round-13 proven body): implicit-GEMM conv via MFMA (bf16x3), all 256
// output channels per block.  (256,3): no spills.
// ---------------------------------------------------------------------------
__global__ __launch_bounds__(256, 3) void conv_gemm(
    const u16* __restrict__ Ah, const u16* __restrict__ Al,
    const float* __restrict__ x, const float* __restrict__ conv_b,
    u16* __restrict__ feat_hi, u16* __restrict__ feat_lo) {
    __shared__ u16 sBh[64 * 72], sBl[64 * 72];
    __shared__ float wls[3 * 9 * 72];
    int tid = threadIdx.x;
    int w = tid >> 6, L = tid & 63;
    int m16 = L & 15, qd = L >> 4;
    int y = blockIdx.x;
    int nb = y << 6;
    int b = blockIdx.y;

    for (int i = tid; i < 3 * 9 * 72; i += 256) wls[i] = 0.f;
    __syncthreads();
    for (int i = tid; i < 3 * 9 * 64; i += 256) {
        int c = i / 576, rem = i - c * 576, wr = rem >> 6, col = rem & 63;
        int iy = y - 4 + wr;
        if (iy >= 0 && iy < 64)
            wls[c * 648 + wr * 72 + 4 + col] = x[((b * 3 + c) << 12) + (iy << 6) + col];
    }
    __syncthreads();

    f32x4 acc[4][4];
    #pragma unroll
    for (int mt = 0; mt < 4; mt++)
        #pragma unroll
        for (int ct = 0; ct < 4; ct++) acc[mt][ct] = (f32x4){0.f, 0.f, 0.f, 0.f};

    int n = tid >> 2, kb = (tid & 3) << 4;
    int arow = w * 16 + m16;

    u16 hbuf[16] __attribute__((aligned(8)));
    u16 lbuf[16] __attribute__((aligned(8)));
    auto build = [&](int kbase) {
        #pragma unroll
        for (int j = 0; j < 16; j++) {
            int k = kbase + kb + j;
            float v = 0.f;
            if (k < 243) {
                int c = (k >= 81) + (k >= 162);
                int rem = k - c * 81;
                int dy = (rem * 57) >> 9;
                int dx = rem - dy * 9;
                v = wls[c * 648 + dy * 72 + dx + n];
            }
            u16 h = f2bf(v);
            hbuf[j] = h;
            lbuf[j] = f2bf(v - bf2f(h));
        }
    };
    build(0);

    for (int k0 = 0; k0 < 256; k0 += 64) {
        short8 afh[4][2], afl[4][2];
        #pragma unroll
        for (int mt = 0; mt < 4; mt++)
            #pragma unroll
            for (int c = 0; c < 2; c++) {
                int ao = (mt * 64 + arow) * 256 + k0 + c * 32 + qd * 8;
                afh[mt][c] = *(const short8*)(Ah + ao);
                afl[mt][c] = *(const short8*)(Al + ao);
            }
        __syncthreads();                    // prior iter's sB reads done
        #pragma unroll
        for (int t = 0; t < 4; t++) {
            *(ushort4*)&sBh[n * 72 + kb + 4 * t] = *(ushort4*)&hbuf[4 * t];
            *(ushort4*)&sBl[n * 72 + kb + 4 * t] = *(ushort4*)&lbuf[4 * t];
        }
        __syncthreads();                    // sB ready
        if (k0 < 192) build(k0 + 64);       // overlaps MFMA below (indep regs)
        #pragma unroll
        for (int c = 0; c < 2; c++) {
            #pragma unroll
            for (int ct = 0; ct < 4; ct++) {
                int bb = (ct * 16 + m16) * 72 + c * 32 + qd * 8;
                short8 bH = *(const short8*)&sBh[bb];
                short8 bL = *(const short8*)&sBl[bb];
                #pragma unroll
                for (int mt = 0; mt < 4; mt++) {
                    acc[mt][ct] = __builtin_amdgcn_mfma_f32_16x16x32_bf16(afh[mt][c], bH, acc[mt][ct], 0, 0, 0);
                    acc[mt][ct] = __builtin_amdgcn_mfma_f32_16x16x32_bf16(afh[mt][c], bL, acc[mt][ct], 0, 0, 0);
                    acc[mt][ct] = __builtin_amdgcn_mfma_f32_16x16x32_bf16(afl[mt][c], bH, acc[mt][ct], 0, 0, 0);
                }
            }
        }
    }

    #pragma unroll
    for (int mt = 0; mt < 4; mt++) {
        #pragma unroll
        for (int i = 0; i < 4; i++) {
            int gr = mt * 64 + w * 16 + qd * 4 + i;
            float bv = conv_b[gr];
            #pragma unroll
            for (int ct = 0; ct < 4; ct++) {
                int gc = nb + ct * 16 + m16;
                float val = fmaxf(acc[mt][ct][i] + bv, 0.f);
                size_t oi = ((size_t)(b * 256 + gr)) * HWd + gc;
                u16 h = f2bf(val);
                feat_hi[oi] = h;
                feat_lo[oi] = f2bf(val - bf2f(h));
            }
        }
    }
}

// ---------------------------------------------------------------------------
// K2: bf16x3 MFMA GEMM with register prefetch + optional K-split.
// mode 0: Co = val + bias.  mode 1: Ch/Cl bf16 hi/lo (+bias).
// mode 2: Co[z*pstride + oi] = val (no bias) — fp32 partial for K-split.
// mode 3: mode 1 + scatter v-columns (gc>=512) into vT[b][h][d][k] (folds
//         the old transpose_v kernel into the qkv epilogue).
// swz=1: 1-D grid, XCD-aware decode — the 4 nb-blocks sharing an A-tile get
// ids differing by 8/16/24 (same id%8 => same XCD, temporally adjacent), so
// the 256KB feat A-tile is fetched from HBM once per XCD instead of 4x
// (consecutive ids round-robin onto different XCDs whose L2s are not
// coherent).  nmt = number of M tiles.
// ---------------------------------------------------------------------------
__global__ __launch_bounds__(256, 4) void gemm_mfma3(
    const u16* __restrict__ Ah, const u16* __restrict__ Al,
    const u16* __restrict__ Bh, const u16* __restrict__ Bl,
    const float* __restrict__ bias,
    float* __restrict__ Co, u16* __restrict__ Ch, u16* __restrict__ Cl,
    u16* __restrict__ vTh, u16* __restrict__ vTl,
    int N, int K, int klen, long long pstride, int mode, int swz, int nmt) {
    __shared__ u16 sAh[64 * 72], sAl[64 * 72], sBh[64 * 72], sBl[64 * 72];
    int tid = threadIdx.x;
    int w = tid >> 6;
    int L = tid & 63;
    int m16 = L & 15, qd = L >> 4;
    int mb, nb, kbeg, zidx;
    if (swz) {
        int blk = blockIdx.x;
        int low = blk & 7, nbi = (blk >> 3) & 3, hi = blk >> 5;
        int idx = low + 8 * hi;           // in [0, 4*nmt)
        int mbi = idx % nmt;
        zidx = idx / nmt;
        nb = nbi * 64; mb = mbi * 64; kbeg = zidx * klen;
    } else {
        nb = blockIdx.x * 64; mb = blockIdx.y * 64;
        zidx = blockIdx.z; kbeg = zidx * klen;
    }

    f32x4 acc[4];
    #pragma unroll
    for (int i = 0; i < 4; i++) acc[i] = (f32x4){0.f, 0.f, 0.f, 0.f};

    int r = tid >> 2, s = tid & 3;
    const u16* pAh = Ah + (size_t)(mb + r) * K + kbeg + s * 16;
    const u16* pAl = Al + (size_t)(mb + r) * K + kbeg + s * 16;
    const u16* pBh = Bh + (size_t)(nb + r) * K + kbeg + s * 16;
    const u16* pBl = Bl + (size_t)(nb + r) * K + kbeg + s * 16;
    u16* dAh = &sAh[r * 72 + s * 16];
    u16* dAl = &sAl[r * 72 + s * 16];
    u16* dBh = &sBh[r * 72 + s * 16];
    u16* dBl = &sBl[r * 72 + s * 16];

    uint4 a0 = *(const uint4*)(pAh);
    uint4 a1 = *(const uint4*)(pAh + 8);
    uint4 a2 = *(const uint4*)(pAl);
    uint4 a3 = *(const uint4*)(pAl + 8);
    uint4 b0 = *(const uint4*)(pBh);
    uint4 b1 = *(const uint4*)(pBh + 8);
    uint4 b2 = *(const uint4*)(pBl);
    uint4 b3 = *(const uint4*)(pBl + 8);

    for (int k0 = 0; k0 < klen; k0 += 64) {
        __syncthreads();
        *(uint4*)(dAh) = a0; *(uint4*)(dAh + 8) = a1;
        *(uint4*)(dAl) = a2; *(uint4*)(dAl + 8) = a3;
        *(uint4*)(dBh) = b0; *(uint4*)(dBh + 8) = b1;
        *(uint4*)(dBl) = b2; *(uint4*)(dBl + 8) = b3;
        __syncthreads();
        int kn = k0 + 64;
        if (kn < klen) {
            a0 = *(const uint4*)(pAh + kn);
            a1 = *(const uint4*)(pAh + kn + 8);
            a2 = *(const uint4*)(pAl + kn);
            a3 = *(const uint4*)(pAl + kn + 8);
            b0 = *(const uint4*)(pBh + kn);
            b1 = *(const uint4*)(pBh + kn + 8);
            b2 = *(const uint4*)(pBl + kn);
            b3 = *(const uint4*)(pBl + kn + 8);
        }
        #pragma unroll
        for (int c = 0; c < 2; c++) {
            int ab = (w * 16 + m16) * 72 + c * 32 + qd * 8;
            short8 aH = *(const short8*)&sAh[ab];
            short8 aL = *(const short8*)&sAl[ab];
            #pragma unroll
            for (int ct = 0; ct < 4; ct++) {
                int bb = (ct * 16 + m16) * 72 + c * 32 + qd * 8;
                short8 bH = *(const short8*)&sBh[bb];
                short8 bL = *(const short8*)&sBl[bb];
                acc[ct] = __builtin_amdgcn_mfma_f32_16x16x32_bf16(aH, bH, acc[ct], 0, 0, 0);
                acc[ct] = __builtin_amdgcn_mfma_f32_16x16x32_bf16(aH, bL, acc[ct], 0, 0, 0);
                acc[ct] = __builtin_amdgcn_mfma_f32_16x16x32_bf16(aL, bH, acc[ct], 0, 0, 0);
            }
        }
    }

    #pragma unroll
    for (int ct = 0; ct < 4; ct++) {
        int gc = nb + ct * 16 + m16;
        float bv = (mode == 2) ? 0.f : bias[gc];
        #pragma unroll
        for (int i = 0; i < 4; i++) {
            int gr = mb + w * 16 + qd * 4 + i;
            float val = acc[ct][i] + bv;
            size_t oi = (size_t)gr * N + gc;
            if (mode == 0) {
                Co[oi] = val;
            } else if (mode == 2) {
                Co[(size_t)zidx * pstride + oi] = val;
            } else {
                u16 h = f2bf(val);
                u16 l = f2bf(val - bf2f(h));
                Ch[oi] = h;
                Cl[oi] = l;
                if (mode == 3 && gc >= 512) {   // V column -> transposed copy
                    int dg = gc - 512, hh = dg >> 5, d = dg & 31;
                    int bb2 = gr >> 8, kr = gr & 255;
                    size_t vi = ((size_t)((bb2 * 8 + hh) * 32 + d)) * 256 + kr;
                    vTh[vi] = h;
                    vTl[vi] = l;
                }
            }
        }
    }
}

// ---------------------------------------------------------------------------
// K3: reduce 4 K-split partials + bias, emit bf16 hi/lo.  N=256 fixed.
// ---------------------------------------------------------------------------
__global__ __launch_bounds__(256) void reduce_split(
    const float* __restrict__ part, const float* __restrict__ bias,
    u16* __restrict__ Ch, u16* __restrict__ Cl, int total) {
    int i = (blockIdx.x * 256 + threadIdx.x) * 4;
    if (i >= total) return;
    float4 s0 = *(const float4*)(part + i);
    float4 s1 = *(const float4*)(part + (size_t)total + i);
    float4 s2 = *(const float4*)(part + 2 * (size_t)total + i);
    float4 s3 = *(const float4*)(part + 3 * (size_t)total + i);
    float4 bv = *(const float4*)(bias + (i & 255));
    float v[4] = { s0.x + s1.x + s2.x + s3.x + bv.x,
                   s0.y + s1.y + s2.y + s3.y + bv.y,
                   s0.z + s1.z + s2.z + s3.z + bv.z,
                   s0.w + s1.w + s2.w + s3.w + bv.w };
    u16 hb[4] __attribute__((aligned(8)));
    u16 lb[4] __attribute__((aligned(8)));
    #pragma unroll
    for (int j = 0; j < 4; j++) {
        u16 h = f2bf(v[j]);
        hb[j] = h;
        lb[j] = f2bf(v[j] - bf2f(h));
    }
    *(ushort4*)(Ch + i) = *(ushort4*)hb;
    *(ushort4*)(Cl + i) = *(ushort4*)lb;
}

// ---------------------------------------------------------------------------
// K4b: MFMA attention.  grid (b, h, qc=4), 256 thr = 4 waves x 16 q-rows.
// ---------------------------------------------------------------------------
__global__ __launch_bounds__(256) void attention_mfma(
    const u16* __restrict__ qkvh, const u16* __restrict__ qkvl,
    const u16* __restrict__ vTh, const u16* __restrict__ vTl,
    float* __restrict__ o) {
    __shared__ u16 ph[4][16][264];
    int b = blockIdx.x, h = blockIdx.y, qc = blockIdx.z;
    int tid = threadIdx.x;
    int w = tid >> 6, L = tid & 63;
    int m16 = L & 15, qd = L >> 4;
    const float rs = 0.17677669529663687f;  // 1/sqrt(32)

    size_t qoff = ((size_t)(b * 256 + qc * 64 + w * 16 + m16)) * 768 + h * 32 + qd * 8;
    short8 qH = *(const short8*)(qkvh + qoff);
    short8 qL = *(const short8*)(qkvl + qoff);

    f32x4 sacc[16];
    #pragma unroll
    for (int nt = 0; nt < 16; nt++) {
        size_t koff = ((size_t)(b * 256 + nt * 16 + m16)) * 768 + 256 + h * 32 + qd * 8;
        short8 bH = *(const short8*)(qkvh + koff);
        short8 bL = *(const short8*)(qkvl + koff);
        f32x4 a = (f32x4){0.f, 0.f, 0.f, 0.f};
        a = __builtin_amdgcn_mfma_f32_16x16x32_bf16(qH, bH, a, 0, 0, 0);
        a = __builtin_amdgcn_mfma_f32_16x16x32_bf16(qH, bL, a, 0, 0, 0);
        a = __builtin_amdgcn_mfma_f32_16x16x32_bf16(qL, bH, a, 0, 0, 0);
        sacc[nt] = a;
    }

    float l4[4] = {0.f, 0.f, 0.f, 0.f};
    #pragma unroll
    for (int nt = 0; nt < 16; nt++)
        #pragma unroll
        for (int i = 0; i < 4; i++) {
            float p = __expf(sacc[nt][i] * rs);
            sacc[nt][i] = p;
            l4[i] += p;
        }
    #pragma unroll
    for (int i = 0; i < 4; i++) {
        l4[i] += __shfl_xor(l4[i], 1);
        l4[i] += __shfl_xor(l4[i], 2);
        l4[i] += __shfl_xor(l4[i], 4);
        l4[i] += __shfl_xor(l4[i], 8);
    }

    #pragma unroll
    for (int nt = 0; nt < 16; nt++)
        #pragma unroll
        for (int i = 0; i < 4; i++)
            ph[w][qd * 4 + i][nt * 16 + m16] = f2bf(sacc[nt][i]);

    f32x4 oacc[2];
    oacc[0] = (f32x4){0.f, 0.f, 0.f, 0.f};
    oacc[1] = (f32x4){0.f, 0.f, 0.f, 0.f};
    size_t vbase = ((size_t)(b * 8 + h)) * 32 * 256;
    #pragma unroll
    for (int kt = 0; kt < 8; kt++) {
        short8 pa = *(const short8*)&ph[w][m16][kt * 32 + qd * 8];
        #pragma unroll
        for (int ct = 0; ct < 2; ct++) {
            size_t voff = vbase + (size_t)(ct * 16 + m16) * 256 + kt * 32 + qd * 8;
            short8 vH = *(const short8*)(vTh + voff);
            short8 vL = *(const short8*)(vTl + voff);
            oacc[ct] = __builtin_amdgcn_mfma_f32_16x16x32_bf16(pa, vH, oacc[ct], 0, 0, 0);
            oacc[ct] = __builtin_amdgcn_mfma_f32_16x16x32_bf16(pa, vL, oacc[ct], 0, 0, 0);
        }
    }

    #pragma unroll
    for (int i = 0; i < 4; i++) {
        float rinv = 1.f / l4[i];
        int orow = b * 256 + qc * 64 + w * 16 + qd * 4 + i;
        #pragma unroll
        for (int ct = 0; ct < 2; ct++)
            o[(size_t)orow * 256 + h * 32 + ct * 16 + m16] = oacc[ct][i] * rinv;
    }
}

// ---------------------------------------------------------------------------
// K5: fused head. One wave per (b,p): tp = tanh(o@M2 + h0); pos embed; patches.
// ---------------------------------------------------------------------------
#define PATCH_OUT 995328   // 16*256*243
__global__ __launch_bounds__(256) void head_kernel(
    const float* __restrict__ o, const float* __restrict__ M2,
    const float* __restrict__ h0, const float* __restrict__ pos_w,
    const float* __restrict__ pos_b, const float* __restrict__ x,
    float* __restrict__ out) {
    int w = threadIdx.x >> 6, lane = threadIdx.x & 63;
    int bp = blockIdx.x * 4 + w;
    int b = bp >> 8;

    const float* orow = o + (size_t)bp * Ed;
    float4 o4 = *(const float4*)(orow + lane * 4);
    int e0 = lane * 4;
    float s0 = o4.x * M2[2 * e0 + 0] + o4.y * M2[2 * e0 + 2] + o4.z * M2[2 * e0 + 4] + o4.w * M2[2 * e0 + 6];
    float s1 = o4.x * M2[2 * e0 + 1] + o4.y * M2[2 * e0 + 3] + o4.z * M2[2 * e0 + 5] + o4.w * M2[2 * e0 + 7];
    #pragma unroll
    for (int off = 32; off; off >>= 1) { s0 += __shfl_xor(s0, off); s1 += __shfl_xor(s1, off); }

    float tx = tanhf(s0 + h0[0]);
    float ty = tanhf(s1 + h0[1]);

    {
        float pv = tx * pos_w[lane] + ty * pos_w[64 + lane] + pos_b[lane];
        out[PATCH_OUT + bp * POSDd + lane] = pv;
    }

    const float* xb = x + b * 3 * HWd;
    #pragma unroll
    for (int s = 0; s < 4; s++) {
        int idx = s * 64 + lane;
        if (idx < 243) {
            int c = idx / 81;
            int rem = idx - c * 81;
            int iy = rem / 9;
            int jx = rem - iy * 9;
            float basex = (2.f * jx + 1.f) / 9.f - 1.f;
            float basey = (2.f * iy + 1.f) / 9.f - 1.f;
            float gx = 0.140625f * basex + tx;
            float gy = 0.140625f * basey + ty;
            float ix  = ((gx + 1.f) * 64.f - 1.f) * 0.5f;
            float iyf = ((gy + 1.f) * 64.f - 1.f) * 0.5f;
            float x0f = floorf(ix), y0f = floorf(iyf);
            float wx = ix - x0f, wy = iyf - y0f;
            int x0i = min(max((int)x0f, 0), 63);
            int x1i = min(max((int)x0f + 1, 0), 63);
            int y0i = min(max((int)y0f, 0), 63);
            int y1i = min(max((int)y0f + 1, 0), 63);
            const float* xc = xb + c * HWd;
            float v00 = xc[y0i * Wd + x0i];
            float v01 = xc[y0i * Wd + x1i];
            float v10 = xc[y1i * Wd + x0i];
            float v11 = xc[y1i * Wd + x1i];
            float val = v00 * (1.f - wx) * (1.f - wy) + v01 * wx * (1.f - wy)
                      + v10 * (1.f - wx) * wy + v11 * wx * wy;
            out[bp * 243 + idx] = val;
        }
    }
}

// ---------------------------------------------------------------------------
extern "C" void kernel_launch(void* const* d_in, const int* in_sizes, int n_in,
                              void* d_out, int out_size, void* d_ws, size_t ws_size,
                              hipStream_t stream) {
    (void)in_sizes; (void)n_in; (void)out_size;
    const float* x      = (const float*)d_in[0];
    const float* conv_w = (const float*)d_in[1];
    const float* conv_b = (const float*)d_in[2];
    const float* in_w   = (const float*)d_in[3];
    const float* in_b   = (const float*)d_in[4];
    const float* wq     = (const float*)d_in[5];
    const float* bq     = (const float*)d_in[6];
    const float* wk     = (const float*)d_in[7];
    const float* bk     = (const float*)d_in[8];
    const float* wv     = (const float*)d_in[9];
    const float* bv     = (const float*)d_in[10];
    const float* wo     = (const float*)d_in[11];
    const float* bo     = (const float*)d_in[12];
    const float* out_w  = (const float*)d_in[13];
    const float* out_b  = (const float*)d_in[14];
    const float* fc_w   = (const float*)d_in[15];
    const float* fc_b   = (const float*)d_in[16];
    const float* pos_w  = (const float*)d_in[17];
    const float* pos_b  = (const float*)d_in[18];

    // ws sizing
    int CB = 16;
    for (;;) {
        size_t u16e = (size_t)(2 * CB + 4) * 1048576 + 2 * 196608 + 2 * 65536
                    + 2 * 3145728 + 2 * 1048576;
        size_t f32e = 768 + 1048576 + 4ull * CB * 65536 + 2048;
        if (u16e * 2 + f32e * 4 <= ws_size || CB == 1) break;
        CB >>= 1;
    }
    int nchunks = 16 / CB;

    char* base = (char*)d_ws;
    u16* feat_hi = (u16*)base;
    u16* feat_lo = feat_hi + (size_t)CB * 1048576;
    u16* tok_hi  = feat_lo + (size_t)CB * 1048576;
    u16* tok_lo  = tok_hi + 1048576;
    u16* inw_h   = tok_lo + 1048576;
    u16* inw_l   = inw_h + 1048576;
    u16* wqkv_h  = inw_l + 1048576;
    u16* wqkv_l  = wqkv_h + 196608;
    u16* convw_h = wqkv_l + 196608;
    u16* convw_l = convw_h + 65536;
    u16* qkvh    = convw_l + 65536;       // 3145728
    u16* qkvl    = qkvh + 3145728;
    u16* vTh     = qkvl + 3145728;        // 1048576
    u16* vTl     = vTh + 1048576;
    float* bqkv  = (float*)(vTl + 1048576);
    float* o     = bqkv + 768;
    float* part  = o + 1048576;           // 4*CB*65536 floats
    float* G     = part + 4ull * CB * 65536;
    float* M2    = G + 512;
    float* h0    = M2 + 512;
    float* out   = (float*)d_out;

    hipLaunchKernelGGL(prep_fused, dim3(626), dim3(256), 0, stream,
                       conv_w, in_w, wq, wk, wv, bq, bk, bv,
                       out_w, fc_w, out_b, fc_b,
                       convw_h, convw_l, inw_h, inw_l,
                       wqkv_h, wqkv_l, bqkv, G, h0);
    hipLaunchKernelGGL(precompute_M2, dim3(258), dim3(64), 0, stream,
                       wo, bo, G, M2, h0);

    for (int c = 0; c < nchunks; ++c) {
        hipLaunchKernelGGL(conv_gemm, dim3(64, CB), dim3(256), 0, stream,
                           convw_h, convw_l,
                           x + (size_t)c * CB * 3 * HWd, conv_b,
                           feat_hi, feat_lo);
        // tok GEMM, K-split 4, XCD-swizzled 1-D grid (64*CB blocks)
        hipLaunchKernelGGL(gemm_mfma3, dim3(64 * CB), dim3(256), 0, stream,
                           feat_hi, feat_lo, inw_h, inw_l, in_b,
                           part, (u16*)nullptr, (u16*)nullptr,
                           (u16*)nullptr, (u16*)nullptr,
                           256, 4096, 1024, (long long)CB * 65536, 2, 1, CB * 4);
        hipLaunchKernelGGL(reduce_split, dim3(CB * 65536 / 1024), dim3(256), 0, stream,
                           part, in_b,
                           tok_hi + (size_t)c * CB * 65536,
                           tok_lo + (size_t)c * CB * 65536,
                           CB * 65536);
    }
    // fused q|k|v GEMM -> bf16 hi/lo qkv, V also scattered into vT (mode 3)
    hipLaunchKernelGGL(gemm_mfma3, dim3(12, 64, 1), dim3(256), 0, stream,
                       tok_hi, tok_lo, wqkv_h, wqkv_l, bqkv,
                       (float*)nullptr, qkvh, qkvl, vTh, vTl,
                       768, 256, 256, 0LL, 3, 0, 64);
    hipLaunchKernelGGL(attention_mfma, dim3(16, 8, 4), dim3(256), 0, stream,
                       qkvh, qkvl, vTh, vTl, o);
    hipLaunchKernelGGL(head_kernel, dim3(1024), dim3(256), 0, stream,
                       o, M2, h0, pos_w, pos_b, x, out);
}